// Round 9
// baseline (268.751 us; speedup 1.0000x reference)
//
#include <hip/hip_runtime.h>
#include <stdint.h>

// x (8,3,40,128,128) f32, W (16,3,3,3,3) f32, b (16) f32.
// conv3d VALID -> softmax(C=16) -> 4x4x4 truncating maxpool -> (8,16,9,31,31).
//
// R9 = R8 with the compile fix (pack bf16 pairs via bf16rnd shifts instead of
// __hip_bfloat162, which isn't trivially copyable for __builtin_bit_cast).
// Single-bf16 x (2^-16 lo-term dropped; W's 2^-9 rounding dominates). LDS
// entry[row][w] = {bf16 x[w] | bf16 x[w+1]<<16}. K=32 covers 8 planes/MFMA
// (4 groups x 2 planes x {kw0,kw1 | 0,kw2}) -> 4 MFMAs/tile, A-frag = 2x
// ds_read2_b32 aligned pairs (no assembly movs). Staging: /33 once,
// incremental addresses, clamped loads. hh unrolled x4, dd rolled.

typedef float f4  __attribute__((ext_vector_type(4)));
typedef short s8v __attribute__((ext_vector_type(8)));
typedef unsigned int u2v __attribute__((ext_vector_type(2), aligned(4)));

#define LOG2E 1.44269504088896340736f

__device__ __host__ inline uint32_t bf16rnd(float x) {
    uint32_t u = __float_as_uint(x);
    return (u + 0x7FFFu + ((u >> 16) & 1u)) >> 16;
}

// B table: 4 MFMAs x 64 lanes x 4 dwords. B[col = lane&15 = oc][k=(g,r,half)]
// plane p = 8m + 2g + (r>>1):
//   r even: {w[kw0] | w[kw1]<<16};  r odd: {0 | w[kw2]<<16};  p>=27 -> 0.
// (A's r-odd low half carries a duplicate x value; B zero kills it.)
__global__ void build_bfrag(const float* __restrict__ W, uint32_t* __restrict__ wd) {
    int idx = blockIdx.x * 256 + threadIdx.x;   // 1024 entries
    if (idx < 1024) {
        int r = idx & 3, l = (idx >> 2) & 63, m = idx >> 8;
        int g = l >> 4, n = l & 15;
        int p = 8 * m + 2 * g + (r >> 1);
        uint32_t v = 0;
        if (p < 27) {
            int ci = p / 9, kd = (p / 3) % 3, kh = p % 3;
            const float* wb = W + (((n * 3 + ci) * 3 + kd) * 3 + kh) * 3;
            if (r & 1) v = bf16rnd(wb[2] * LOG2E) << 16;
            else       v = bf16rnd(wb[0] * LOG2E) | (bf16rnd(wb[1] * LOG2E) << 16);
        }
        wd[idx] = v;
    }
}

template<int CTRL>
__device__ inline float dppror(float v) {
    return __int_as_float(__builtin_amdgcn_update_dpp(
        0, __float_as_int(v), CTRL, 0xF, 0xF, true));
}
__device__ inline float allsum16(float v) {   // all-reduce add within 16-lane row
    v += dppror<0x121>(v);
    v += dppror<0x122>(v);
    v += dppror<0x124>(v);
    v += dppror<0x128>(v);
    return v;
}

__global__ __launch_bounds__(256, 4)
void conv_softmax_pool(const float* __restrict__ x,
                       const float* __restrict__ bias,
                       const uint32_t* __restrict__ wd,
                       float* __restrict__ out) {
    const int bid = blockIdx.x;
    const int wt  = bid & 1;            // w-tile: wo 0..15 / 16..30
    const int ho  = (bid >> 1) % 31;
    const int dpo = (bid / 62) % 9;
    const int b   = bid / 558;          // 558 = 2*31*9

    const int w0 = wt * 64;
    const int h0 = ho * 4;
    const int d0 = dpo * 4;

    __shared__ uint32_t xs[108 * 66];   // 28512 B; row = (ci*6+d)*6+h

    const int tid = threadIdx.x;

    // ---- stage: entry[row][w] = {bf16(x[w]) | bf16(x[w+1])<<16} ----
    {
        const int h  = tid / 33;        // 0..5 for tid<198
        const int pw = tid % 33;        // entry pair 2pw, 2pw+1
        int gwb = w0 + 2 * pw; if (gwb > 124) gwb = 124;   // clamp: extras feed discarded cols
        const float* xp = x + (size_t)b * (3ull * 40 * 128 * 128)
                            + (size_t)d0 * 16384
                            + (size_t)(h0 + h) * 128 + gwb;
        uint32_t wb = (uint32_t)(h * 264 + 8 * pw);
        if (tid < 198) {
            #pragma unroll 1
            for (int ci = 0; ci < 3; ++ci) {
                #pragma unroll 1
                for (int d = 0; d < 6; ++d) {
                    float2 v01 = *(const float2*)xp;
                    float  v2  = xp[2];
                    uint2 pr = make_uint2(bf16rnd(v01.x) | (bf16rnd(v01.y) << 16),
                                          bf16rnd(v01.y) | (bf16rnd(v2)   << 16));
                    *(uint2*)((char*)xs + wb) = pr;
                    xp += 16384;
                    wb += 1584;
                }
                xp += 34 * 16384;       // (40-6) planes to next ci
            }
        }
    }

    const int lane = tid & 63;
    const int wv   = tid >> 6;          // wave: w positions [16wv, 16wv+16)
    const int nn   = lane & 15;         // A-row = position; D-col = oc
    const int g    = lane >> 4;

    // weight B-fragments (4 MFMAs)
    s8v bS[4];
    {
        const uint4* wsp = (const uint4*)wd;
        #pragma unroll
        for (int m = 0; m < 4; ++m)
            bS[m] = __builtin_bit_cast(s8v, wsp[m * 64 + lane]);
    }
    // per-lane plane base addresses (2 planes per MFMA; clamp -> B is 0)
    const char* aA[4];
    const char* aB[4];
    #pragma unroll
    for (int m = 0; m < 4; ++m) {
        int pa = 8 * m + 2 * g;     if (pa > 26) pa = 26;
        int pb = 8 * m + 2 * g + 1; if (pb > 26) pb = 26;
        int ra = (pa / 9 * 6 + (pa / 3) % 3) * 6 + pa % 3;
        int rb = (pb / 9 * 6 + (pb / 3) % 3) * 6 + pb % 3;
        aA[m] = (const char*)xs + ra * 264 + (16 * wv + nn) * 4;
        aB[m] = (const char*)xs + rb * 264 + (16 * wv + nn) * 4;
    }
    const float bl = bias[nn] * LOG2E;

    __syncthreads();

    float pool = 0.0f;
    #pragma unroll 1
    for (int dd = 0; dd < 4; ++dd) {
        #pragma unroll
        for (int hh = 0; hh < 4; ++hh) {
            f4 acc = {bl, bl, bl, bl};
            #pragma unroll
            for (int m = 0; m < 4; ++m) {
                u2v ra = *(const u2v*)(aA[m] + hh * 264);   // ds_read2_b32
                u2v rb = *(const u2v*)(aB[m] + hh * 264);
                union { uint32_t u[4]; s8v s; } A;
                A.u[0] = ra.x; A.u[1] = ra.y; A.u[2] = rb.x; A.u[3] = rb.y;
                acc = __builtin_amdgcn_mfma_f32_16x16x32_bf16(A.s, bS[m], acc, 0, 0, 0);
            }
            // softmax over oc (16-lane rows), raw exp2 (|arg| < ~9, safe)
            float e0 = __builtin_amdgcn_exp2f(acc[0]);
            float e1 = __builtin_amdgcn_exp2f(acc[1]);
            float e2 = __builtin_amdgcn_exp2f(acc[2]);
            float e3 = __builtin_amdgcn_exp2f(acc[3]);
            float p0 = e0 * __builtin_amdgcn_rcpf(allsum16(e0));
            float p1 = e1 * __builtin_amdgcn_rcpf(allsum16(e1));
            float p2 = e2 * __builtin_amdgcn_rcpf(allsum16(e2));
            float p3 = e3 * __builtin_amdgcn_rcpf(allsum16(e3));
            // regs = w positions 4g..4g+3 = one pooled w-cell
            pool = fmaxf(pool, fmaxf(fmaxf(p0, p1), fmaxf(p2, p3)));
        }
        #pragma unroll
        for (int m = 0; m < 4; ++m) { aA[m] += 1584; aB[m] += 1584; }
    }

    // lane holds pooled value for (oc = nn, w-cell = g)
    {
        int wo = wt * 16 + wv * 4 + g;
        if (wo < 31)
            out[(((size_t)b * 16 + nn) * 9 + dpo) * 961
                + (size_t)ho * 31 + wo] = pool;
    }
}

extern "C" void kernel_launch(void* const* d_in, const int* in_sizes, int n_in,
                              void* d_out, int out_size, void* d_ws, size_t ws_size,
                              hipStream_t stream) {
    const float* x  = (const float*)d_in[0];
    const float* W  = (const float*)d_in[1];
    const float* bb = (const float*)d_in[2];
    float* out = (float*)d_out;

    hipLaunchKernelGGL(build_bfrag, dim3(4), dim3(256), 0, stream,
                       W, (uint32_t*)d_ws);

    const int blocks = 8 * 9 * 31 * 2;  // 4464
    hipLaunchKernelGGL(conv_softmax_pool, dim3(blocks), dim3(256), 0, stream,
                       x, bb, (const uint32_t*)d_ws, out);
}

// Round 10
// 63.998 us; speedup vs baseline: 4.1993x; 4.1993x over previous
//
#include <hip/hip_runtime.h>
#include <stdint.h>

// x (8,3,40,128,128) f32, W (16,3,3,3,3) f32, b (16) f32.
// conv3d VALID -> softmax(C=16) -> 4x4x4 truncating maxpool -> (8,16,9,31,31).
//
// R10 = R9's validated numerics (single-bf16 x, 4 MFMAs/tile, paired-plane B
// table) on R7's proven schedule skeleton:
//  - direct xs[] indexing (addrspace(3) provenance trivial; R9's mutated
//    generic char* pointer arrays stalled the machine at 95% idle),
//  - static per-lane dword offsets pA[m]/pB[m], tile base recomputed per
//    rolled dd/hh iteration (no loop-carried pointer state),
//  - R7's 256-thread staging loop (independent iterations, single clamp).

typedef float f4  __attribute__((ext_vector_type(4)));
typedef short s8v __attribute__((ext_vector_type(8)));
typedef unsigned int u2v __attribute__((ext_vector_type(2), aligned(4)));

#define LOG2E 1.44269504088896340736f

__device__ __host__ inline uint32_t bf16rnd(float x) {
    uint32_t u = __float_as_uint(x);
    return (u + 0x7FFFu + ((u >> 16) & 1u)) >> 16;
}

// B table: 4 MFMAs x 64 lanes x 4 dwords. B[col = lane&15 = oc][k=(g,r,half)]
// plane p = 8m + 2g + (r>>1):
//   r even: {w[kw0] | w[kw1]<<16};  r odd: {0 | w[kw2]<<16};  p>=27 -> 0.
// (A's r-odd low half carries a duplicate x value; B zero kills it.)
// Validated by R9 (passed, absmax 1.95e-3).
__global__ void build_bfrag(const float* __restrict__ W, uint32_t* __restrict__ wd) {
    int idx = blockIdx.x * 256 + threadIdx.x;   // 1024 entries
    if (idx < 1024) {
        int r = idx & 3, l = (idx >> 2) & 63, m = idx >> 8;
        int g = l >> 4, n = l & 15;
        int p = 8 * m + 2 * g + (r >> 1);
        uint32_t v = 0;
        if (p < 27) {
            int ci = p / 9, kd = (p / 3) % 3, kh = p % 3;
            const float* wb = W + (((n * 3 + ci) * 3 + kd) * 3 + kh) * 3;
            if (r & 1) v = bf16rnd(wb[2] * LOG2E) << 16;
            else       v = bf16rnd(wb[0] * LOG2E) | (bf16rnd(wb[1] * LOG2E) << 16);
        }
        wd[idx] = v;
    }
}

template<int CTRL>
__device__ inline float dppror(float v) {
    return __int_as_float(__builtin_amdgcn_update_dpp(
        0, __float_as_int(v), CTRL, 0xF, 0xF, true));
}
__device__ inline float allsum16(float v) {   // all-reduce add within 16-lane row
    v += dppror<0x121>(v);
    v += dppror<0x122>(v);
    v += dppror<0x124>(v);
    v += dppror<0x128>(v);
    return v;
}

__global__ __launch_bounds__(256, 4)
void conv_softmax_pool(const float* __restrict__ x,
                       const float* __restrict__ bias,
                       const uint32_t* __restrict__ wd,
                       float* __restrict__ out) {
    const int bid = blockIdx.x;
    const int wt  = bid & 1;            // w-tile: wo 0..15 / 16..30
    const int ho  = (bid >> 1) % 31;
    const int dpo = (bid / 62) % 9;
    const int b   = bid / 558;          // 558 = 2*31*9

    const int w0 = wt * 64;
    const int h0 = ho * 4;
    const int d0 = dpo * 4;

    __shared__ uint32_t xs[108 * 66];   // 28512 B; row = (ci*6+d)*6+h
                                        // entry[row][w] = {bf16 x[w] | bf16 x[w+1]<<16}

    const int tid = threadIdx.x;

    // ---- stage (R7 loop shape): 3564 pair-writes across 256 threads ----
    const size_t xbase = (size_t)b * (3ull * 40 * 128 * 128);
    #pragma unroll 1
    for (int it = 0; it < 14; ++it) {
        int idx = tid + it * 256;
        if (idx < 3564) {
            int pw  = idx % 33;          // entries 2pw, 2pw+1
            int row = idx / 33;          // = (ci*6+d)*6+h
            int h   = row % 6;
            int d   = (row / 6) % 6;
            int ci  = row / 36;
            int gw = w0 + 2 * pw;
            if (gw > 124) gw = 124;      // extras feed discarded cols only
            const float* xp = x + xbase + ((size_t)ci * 40 + (d0 + d)) * 16384
                                        + (size_t)(h0 + h) * 128 + gw;
            float2 v01 = *(const float2*)xp;
            float  v2  = xp[2];
            uint2 pr = make_uint2(bf16rnd(v01.x) | (bf16rnd(v01.y) << 16),
                                  bf16rnd(v01.y) | (bf16rnd(v2)   << 16));
            *(uint2*)&xs[row * 66 + 2 * pw] = pr;
        }
    }

    const int lane = tid & 63;
    const int wv   = tid >> 6;          // wave: w positions [16wv, 16wv+16)
    const int nn   = lane & 15;         // A-row = position; D-col = oc
    const int g    = lane >> 4;

    // weight B-fragments (4 MFMAs)
    s8v bS[4];
    {
        const uint4* wsp = (const uint4*)wd;
        #pragma unroll
        for (int m = 0; m < 4; ++m)
            bS[m] = __builtin_bit_cast(s8v, wsp[m * 64 + lane]);
    }
    // per-lane static plane dword-offsets (2 planes per MFMA; clamp -> B is 0)
    uint32_t pA[4], pB[4];
    #pragma unroll
    for (int m = 0; m < 4; ++m) {
        int pa = 8 * m + 2 * g;     if (pa > 26) pa = 26;
        int pb = 8 * m + 2 * g + 1; if (pb > 26) pb = 26;
        pA[m] = (uint32_t)((pa / 9 * 6 + (pa / 3) % 3) * 6 + pa % 3) * 66u;
        pB[m] = (uint32_t)((pb / 9 * 6 + (pb / 3) % 3) * 6 + pb % 3) * 66u;
    }
    const uint32_t base0 = (uint32_t)(16 * wv + nn);
    const float bl = bias[nn] * LOG2E;

    __syncthreads();

    float pool = 0.0f;
    #pragma unroll 1
    for (int dd = 0; dd < 4; ++dd) {
        #pragma unroll 1
        for (int hh = 0; hh < 4; ++hh) {
            const uint32_t tb = base0 + (uint32_t)((dd * 6 + hh) * 66);
            f4 acc = {bl, bl, bl, bl};
            #pragma unroll
            for (int m = 0; m < 4; ++m) {
                u2v ra = *(const u2v*)&xs[tb + pA[m]];   // ds_read2_b32
                u2v rb = *(const u2v*)&xs[tb + pB[m]];
                union { uint32_t u[4]; s8v s; } A;
                A.u[0] = ra.x; A.u[1] = ra.y; A.u[2] = rb.x; A.u[3] = rb.y;
                acc = __builtin_amdgcn_mfma_f32_16x16x32_bf16(A.s, bS[m], acc, 0, 0, 0);
            }
            // softmax over oc (16-lane rows), raw exp2 (|arg| < ~9, safe)
            float e0 = __builtin_amdgcn_exp2f(acc[0]);
            float e1 = __builtin_amdgcn_exp2f(acc[1]);
            float e2 = __builtin_amdgcn_exp2f(acc[2]);
            float e3 = __builtin_amdgcn_exp2f(acc[3]);
            float p0 = e0 * __builtin_amdgcn_rcpf(allsum16(e0));
            float p1 = e1 * __builtin_amdgcn_rcpf(allsum16(e1));
            float p2 = e2 * __builtin_amdgcn_rcpf(allsum16(e2));
            float p3 = e3 * __builtin_amdgcn_rcpf(allsum16(e3));
            // regs = w positions 4g..4g+3 = one pooled w-cell
            pool = fmaxf(pool, fmaxf(fmaxf(p0, p1), fmaxf(p2, p3)));
        }
    }

    // lane holds pooled value for (oc = nn, w-cell = g)
    {
        int wo = wt * 16 + wv * 4 + g;
        if (wo < 31)
            out[(((size_t)b * 16 + nn) * 9 + dpo) * 961
                + (size_t)ho * 31 + wo] = pool;
    }
}

extern "C" void kernel_launch(void* const* d_in, const int* in_sizes, int n_in,
                              void* d_out, int out_size, void* d_ws, size_t ws_size,
                              hipStream_t stream) {
    const float* x  = (const float*)d_in[0];
    const float* W  = (const float*)d_in[1];
    const float* bb = (const float*)d_in[2];
    float* out = (float*)d_out;

    hipLaunchKernelGGL(build_bfrag, dim3(4), dim3(256), 0, stream,
                       W, (uint32_t*)d_ws);

    const int blocks = 8 * 9 * 31 * 2;  // 4464
    hipLaunchKernelGGL(conv_softmax_pool, dim3(blocks), dim3(256), 0, stream,
                       x, bb, (const uint32_t*)d_ws, out);
}